// Round 1
// baseline (464.625 us; speedup 1.0000x reference)
//
#include <hip/hip_runtime.h>
#include <stdint.h>

typedef __attribute__((ext_vector_type(8)))  short   short8;
typedef __attribute__((ext_vector_type(4)))  short   short4v;
typedef __attribute__((ext_vector_type(16))) float   floatx16;

#define B_    64
#define CIN   64
#define COUT  128
#define T_    300
#define V_    25
#define TV    (T_ * V_)          // 7500
#define NRED  (B_ * T_ * V_)     // 480000 elements per channel
#define NSLOTS 32
#define EPS   1e-5f

// ws layout (bytes):
//   [0,      16384)  wsW   : 8192 bf16  W A-fragments
//   [16384,  18432)  wsAdj : 1024 bf16  adj B-fragments (zero-padded to 32x32)
//   [18432,  34816)  psum  : 32*128 f32 partial sums
//   [34816,  51200)  psq   : 32*128 f32 partial sum-of-squares
//   [51200,  51712)  scale : 128 f32
//   [51712,  52224)  shift : 128 f32

__device__ __forceinline__ unsigned short f2bf(float f) {
    union { float f; uint32_t u; } c; c.f = f;
    uint32_t u = c.u;
    u += 0x7FFFu + ((u >> 16) & 1u);   // round-to-nearest-even
    return (unsigned short)(u >> 16);
}

__device__ __forceinline__ floatx16 fzero16() {
    floatx16 z;
#pragma unroll
    for (int i = 0; i < 16; ++i) z[i] = 0.f;
    return z;
}

// Pack W into A-fragment order and adj into B-fragment order (bf16).
// W frag:  wsW[((w*4+kk)*64 + l)*8 + j] = W[32*w + (l&31)][16*kk + 8*(l>>5) + j]
// adj frag: wsAdj[(s*64 + l)*8 + j]     = adjp[16*s + 8*(l>>5) + j][l&31]  (zero pad >=25)
__global__ void pack_kernel(const float* __restrict__ W, const float* __restrict__ adj,
                            unsigned short* __restrict__ wsW, unsigned short* __restrict__ wsAdj) {
    int stride = blockDim.x * gridDim.x;
    for (int idx = threadIdx.x + blockIdx.x * blockDim.x; idx < 8192; idx += stride) {
        int j  = idx & 7;
        int l  = (idx >> 3) & 63;
        int kk = (idx >> 9) & 3;
        int w  = idx >> 11;
        int o  = 32 * w + (l & 31);
        int c  = 16 * kk + 8 * (l >> 5) + j;
        wsW[idx] = f2bf(W[o * CIN + c]);
    }
    for (int idx = threadIdx.x + blockIdx.x * blockDim.x; idx < 1024; idx += stride) {
        int j = idx & 7;
        int l = (idx >> 3) & 63;
        int s = idx >> 9;
        int k = 16 * s + 8 * (l >> 5) + j;   // v index
        int n = l & 31;                       // w index
        float v = (k < V_ && n < V_) ? adj[k * V_ + n] : 0.f;
        wsAdj[idx] = f2bf(v);
    }
}

// Main fused kernel. WRITE=false: accumulate per-channel sum/sumsq partials.
// WRITE=true: apply scale/shift + relu and store output.
// Block: 256 threads (4 waves). Grid: (75, 64) -> 4 consecutive t per block, b = blockIdx.y.
// Waves (0,1) compute G for t_even (c-tiles 0,1); waves (2,3) for t_odd.
// Then every wave computes its 32-row o-tile of Y for both t's.
template <bool WRITE>
__global__ __launch_bounds__(256) void main_kernel(
    const float* __restrict__ x,
    const unsigned short* __restrict__ wsW,
    const unsigned short* __restrict__ wsAdj,
    const float* __restrict__ scale, const float* __restrict__ shift,
    float* __restrict__ psum, float* __restrict__ psq,
    float* __restrict__ out)
{
    __shared__ unsigned short Gbuf[2][2048] __attribute__((aligned(16)));

    const int tid  = threadIdx.x;
    const int wave = tid >> 6;
    const int lane = tid & 63;
    const int q    = lane >> 5;     // half-wave index
    const int ln   = lane & 31;
    const int b    = blockIdx.y;
    const int t0   = blockIdx.x * 4;
    const int ctile = wave & 1;
    const int tsel  = wave >> 1;

    // Loop-invariant fragments: W (A-layout) and adj (B-layout) straight into registers.
    short8 wf[4];
#pragma unroll
    for (int kk = 0; kk < 4; ++kk)
        wf[kk] = ((const short8*)wsW)[(wave * 4 + kk) * 64 + lane];
    short8 af[2];
#pragma unroll
    for (int s = 0; s < 2; ++s)
        af[s] = ((const short8*)wsAdj)[s * 64 + lane];

    float sc[16], sh[16], sums[16], sqs[16];
    if (WRITE) {
#pragma unroll
        for (int r = 0; r < 16; ++r) {
            int row = 32 * wave + (r & 3) + 8 * (r >> 2) + 4 * q;
            sc[r] = scale[row];
            sh[r] = shift[row];
        }
    } else {
#pragma unroll
        for (int r = 0; r < 16; ++r) { sums[r] = 0.f; sqs[r] = 0.f; }
    }

    for (int iter = 0; iter < 2; ++iter) {
        const int t = t0 + iter * 2 + tsel;
        const float* xrow = x + ((size_t)(b * CIN + 32 * ctile + ln) * T_ + t) * V_;

        // X A-fragments (bf16). kstep0: v = 8q+j ; kstep1: v = 16+8q+j (zero past v=24)
        short8 xa0, xa1;
#pragma unroll
        for (int j = 0; j < 8; ++j) xa0[j] = (short)f2bf(xrow[8 * q + j]);
        if (q == 0) {
#pragma unroll
            for (int j = 0; j < 8; ++j) xa1[j] = (short)f2bf(xrow[16 + j]);
        } else {
            xa1[0] = (short)f2bf(xrow[24]);
#pragma unroll
            for (int j = 1; j < 8; ++j) xa1[j] = 0;
        }

        // G = X @ adjp  (32x32 tile of rows 32*ctile..+31, all 32 cols; cols>=25 are 0)
        floatx16 g = fzero16();
        g = __builtin_amdgcn_mfma_f32_32x32x16_bf16(xa0, af[0], g, 0, 0, 0);
        g = __builtin_amdgcn_mfma_f32_32x32x16_bf16(xa1, af[1], g, 0, 0, 0);

        __syncthreads();   // previous iteration's Gbuf reads complete before overwrite

        // Pack G (C-layout) -> LDS in B-fragment order:
        // element (c_local = (r&3)+8*(r>>2)+4q, w = ln) -> Gbuf[((c>>3)*32 + w)*8 + (c&7)]
#pragma unroll
        for (int r1 = 0; r1 < 4; ++r1) {
            short4v p;
#pragma unroll
            for (int r0 = 0; r0 < 4; ++r0) p[r0] = (short)f2bf(g[r1 * 4 + r0]);
            *(short4v*)&Gbuf[tsel][((4 * ctile + r1) * 32 + ln) * 8 + 4 * q] = p;
        }

        __syncthreads();

        // Y = W @ G for both t's; this wave's o-tile = rows 32*wave..+31
#pragma unroll
        for (int ts = 0; ts < 2; ++ts) {
            floatx16 acc = fzero16();
#pragma unroll
            for (int kk = 0; kk < 4; ++kk) {
                short8 bfrag = *(const short8*)&Gbuf[ts][((kk * 2 + q) * 32 + ln) * 8];
                acc = __builtin_amdgcn_mfma_f32_32x32x16_bf16(wf[kk], bfrag, acc, 0, 0, 0);
            }
            if (WRITE) {
                const int t_out = t0 + iter * 2 + ts;
                if (ln < V_) {
                    float* obase = out + ((size_t)(b * COUT + 32 * wave) * T_ + t_out) * V_ + ln;
#pragma unroll
                    for (int r = 0; r < 16; ++r) {
                        int row = (r & 3) + 8 * (r >> 2) + 4 * q;
                        float v = sc[r] * acc[r] + sh[r];
                        obase[(size_t)row * TV] = v > 0.f ? v : 0.f;
                    }
                }
            } else {
#pragma unroll
                for (int r = 0; r < 16; ++r) {
                    sums[r] += acc[r];
                    sqs[r]  += acc[r] * acc[r];
                }
            }
        }
    }

    if (!WRITE) {
        // Reduce across the 32 lanes of each half-wave (cols), then one atomic per channel.
#pragma unroll
        for (int r = 0; r < 16; ++r) {
            float s = sums[r], ss = sqs[r];
#pragma unroll
            for (int m = 1; m <= 16; m <<= 1) {
                s  += __shfl_xor(s,  m, 64);
                ss += __shfl_xor(ss, m, 64);
            }
            sums[r] = s; sqs[r] = ss;
        }
        if (ln == 0) {
            int slot = (blockIdx.y * 75 + blockIdx.x) & (NSLOTS - 1);
#pragma unroll
            for (int r = 0; r < 16; ++r) {
                int ch = 32 * wave + (r & 3) + 8 * (r >> 2) + 4 * q;
                atomicAdd(&psum[slot * COUT + ch], sums[r]);
                atomicAdd(&psq [slot * COUT + ch], sqs[r]);
            }
        }
    }
}

__global__ void stats_kernel(const float* __restrict__ psum, const float* __restrict__ psq,
                             const float* __restrict__ gamma, const float* __restrict__ beta,
                             float* __restrict__ scale, float* __restrict__ shift) {
    int o = threadIdx.x;   // 128 threads
    float s = 0.f, ss = 0.f;
    for (int k = 0; k < NSLOTS; ++k) {
        s  += psum[k * COUT + o];
        ss += psq [k * COUT + o];
    }
    float mean = s / (float)NRED;
    float var  = ss / (float)NRED - mean * mean;
    float inv  = rsqrtf(var + EPS);
    float scv  = gamma[o] * inv;
    scale[o] = scv;
    shift[o] = beta[o] - mean * scv;
}

extern "C" void kernel_launch(void* const* d_in, const int* in_sizes, int n_in,
                              void* d_out, int out_size, void* d_ws, size_t ws_size,
                              hipStream_t stream) {
    const float* x     = (const float*)d_in[0];
    const float* adj   = (const float*)d_in[1];
    const float* W     = (const float*)d_in[2];
    // d_in[3] = conv bias: mathematically cancelled by BatchNorm (training mode) -> unused
    const float* gamma = (const float*)d_in[4];
    const float* beta  = (const float*)d_in[5];
    float* out = (float*)d_out;

    char* ws = (char*)d_ws;
    unsigned short* wsW   = (unsigned short*)(ws);
    unsigned short* wsAdj = (unsigned short*)(ws + 16384);
    float* psum  = (float*)(ws + 18432);
    float* psq   = (float*)(ws + 34816);
    float* scale = (float*)(ws + 51200);
    float* shift = (float*)(ws + 51712);

    // zero the stat partials (ws is poisoned before every launch)
    hipMemsetAsync(psum, 0, 2 * NSLOTS * COUT * sizeof(float), stream);

    pack_kernel<<<8, 256, 0, stream>>>(W, adj, wsW, wsAdj);

    dim3 grid(75, 64);
    main_kernel<false><<<grid, 256, 0, stream>>>(x, wsW, wsAdj, nullptr, nullptr, psum, psq, nullptr);
    stats_kernel<<<1, 128, 0, stream>>>(psum, psq, gamma, beta, scale, shift);
    main_kernel<true><<<grid, 256, 0, stream>>>(x, wsW, wsAdj, scale, shift, psum, psq, out);
}